// Round 7
// baseline (3276.469 us; speedup 1.0000x reference)
//
#include <hip/hip_runtime.h>
#include <hip/hip_bf16.h>

// ---------------- problem constants (fixed by setup_inputs) ----------------
constexpr int B_  = 8;
constexpr int H_  = 64;
constexpr int W_  = 64;
constexpr int C_  = 192;
constexpr int Dn  = 192;
constexpr int Nst = 8;    // state dim N
constexpr int R_  = 12;
constexpr int K_  = 4;    // directions
constexpr int L_  = H_ * W_;          // 4096
constexpr int CS  = 32;               // scan chunk size
constexpr int NC  = L_ / CS;          // 128 chunks per chain
constexpr int CPROJ = R_ + 2 * Nst;   // 28
constexpr int MROWS = B_ * L_;        // 32768
constexpr int NBLK  = B_ * K_ * NC;   // 4096 scan blocks

typedef __attribute__((ext_vector_type(8))) short short8v;
typedef __attribute__((ext_vector_type(4))) float f32x4;

// t -> spatial position for direction k (verified round 0).
// Within a chunk: lm = map_t(k,t0) + ts*stride (no wrap since CS | 64).
__device__ __forceinline__ int map_t(int k, int t) {
    int tt = (k >= 2) ? (L_ - 1 - t) : t;
    if (k & 1) tt = (tt & 63) * 64 + (tt >> 6);
    return tt;
}

__device__ __forceinline__ short f2bf(float f) {   // round-to-nearest-even
    unsigned u = __float_as_uint(f);
    u += 0x7FFFu + ((u >> 16) & 1u);
    return (short)(u >> 16);
}
__device__ __forceinline__ float bf2f(short s) {
    return __uint_as_float(((unsigned)(unsigned short)s) << 16);
}

// ---------------- fused f32 -> bf16 convert (x and all weights) -------------
constexpr int WOFF_IN  = 0;               // w_in  (384x192)
constexpr int WOFF_XP  = 73728;           // xpw   (112x192)
constexpr int WOFF_OUT = 95232;           // wout  (192x192)
constexpr int WTOTAL   = 132096;
constexpr int XUNITS   = MROWS * Dn / 8;  // 786432
constexpr int WUNITS   = WTOTAL / 8;      // 16512
__global__ __launch_bounds__(256) void k_cvt(const float* __restrict__ x,
                                             const float* __restrict__ w_in,
                                             const float* __restrict__ xpw,
                                             const float* __restrict__ wout,
                                             short* __restrict__ x_bf,
                                             short* __restrict__ w_bf) {
    int g = blockIdx.x * 256 + threadIdx.x;
    const float* src;
    short* dst;
    int off;
    if (g < XUNITS) { src = x; dst = x_bf; off = g * 8; }
    else {
        g -= XUNITS;
        if (g >= WUNITS) return;
        int base = g * 8;
        dst = w_bf; off = base;
        if (base < WOFF_XP)       { src = w_in; }
        else if (base < WOFF_OUT) { src = xpw;  src -= WOFF_XP; }
        else                      { src = wout; src -= WOFF_OUT; }
    }
    float4 a = *reinterpret_cast<const float4*>(src + off);
    float4 b = *reinterpret_cast<const float4*>(src + off + 4);
    short8v v = {f2bf(a.x), f2bf(a.y), f2bf(a.z), f2bf(a.w),
                 f2bf(b.x), f2bf(b.y), f2bf(b.z), f2bf(b.w)};
    *reinterpret_cast<short8v*>(dst + off) = v;
}

// ---------------- bf16 MFMA GEMM cores --------------------------------------
__device__ __forceinline__ void mgemm_core(const short* __restrict__ A,
                                           const short* __restrict__ Wb,
                                           f32x4 (&acc)[4][2],
                                           int mrow, int ncol, int Nact, int K) {
    const int lane = threadIdx.x & 63;
    const int koff = (lane >> 4) * 8;
    for (int k0 = 0; k0 < K; k0 += 32) {
        short8v af[4], bfr[2];
#pragma unroll
        for (int mf = 0; mf < 4; mf++)
            af[mf] = *reinterpret_cast<const short8v*>(
                A + (size_t)(mrow + mf * 16) * K + k0 + koff);
#pragma unroll
        for (int nf = 0; nf < 2; nf++) {
            int r = ncol + nf * 16;
            short8v z = {0, 0, 0, 0, 0, 0, 0, 0};
            bfr[nf] = (r < Nact)
                ? *reinterpret_cast<const short8v*>(Wb + (size_t)r * K + k0 + koff)
                : z;
        }
#pragma unroll
        for (int mf = 0; mf < 4; mf++)
#pragma unroll
            for (int nf = 0; nf < 2; nf++)
                acc[mf][nf] = __builtin_amdgcn_mfma_f32_16x16x32_bf16(
                    af[mf], bfr[nf], acc[mf][nf], 0, 0, 0);
    }
}

// f32-output GEMM (x_proj, out_proj)
__global__ __launch_bounds__(256) void k_mgemm_f(const short* __restrict__ A,
                                                 const short* __restrict__ Wb,
                                                 float* __restrict__ out0,
                                                 int Nact, int K) {
    const int m0 = blockIdx.x * 128, n0 = blockIdx.y * 64;
    const int wid = threadIdx.x >> 6, lane = threadIdx.x & 63;
    const int wm = wid >> 1, wn = wid & 1;
    f32x4 acc[4][2] = {};
    mgemm_core(A, Wb, acc, m0 + wm * 64 + (lane & 15), n0 + wn * 32 + (lane & 15),
               Nact, K);
    const int prow = (lane >> 4) * 4, pcol = lane & 15;
#pragma unroll
    for (int mf = 0; mf < 4; mf++) {
        int mbase = m0 + wm * 64 + mf * 16 + prow;
#pragma unroll
        for (int nf = 0; nf < 2; nf++) {
            int n = n0 + wn * 32 + nf * 16 + pcol;
            if (n >= Nact) continue;
#pragma unroll
            for (int r = 0; r < 4; r++)
                out0[(size_t)(mbase + r) * Nact + n] = acc[mf][nf][r];
        }
    }
}

// in_proj: split bf16 outputs (xf | z), each ldc=192
__global__ __launch_bounds__(256) void k_mgemm_in(const short* __restrict__ A,
                                                  const short* __restrict__ Wb,
                                                  short* __restrict__ xf_bf,
                                                  short* __restrict__ z_bf,
                                                  int K) {
    const int m0 = blockIdx.x * 128, n0 = blockIdx.y * 64;
    const int wid = threadIdx.x >> 6, lane = threadIdx.x & 63;
    const int wm = wid >> 1, wn = wid & 1;
    f32x4 acc[4][2] = {};
    mgemm_core(A, Wb, acc, m0 + wm * 64 + (lane & 15), n0 + wn * 32 + (lane & 15),
               384, K);
    const int prow = (lane >> 4) * 4, pcol = lane & 15;
#pragma unroll
    for (int mf = 0; mf < 4; mf++) {
        int mbase = m0 + wm * 64 + mf * 16 + prow;
#pragma unroll
        for (int nf = 0; nf < 2; nf++) {
            int n = n0 + wn * 32 + nf * 16 + pcol;
#pragma unroll
            for (int r = 0; r < 4; r++) {
                int m = mbase + r;
                if (n < 192) xf_bf[(size_t)m * 192 + n] = f2bf(acc[mf][nf][r]);
                else         z_bf[(size_t)m * 192 + (n - 192)] = f2bf(acc[mf][nf][r]);
            }
        }
    }
}

// ---------------- depthwise 3x3 conv + bias + SiLU (bf16 in/out) ------------
__global__ __launch_bounds__(256) void k_conv(const short* __restrict__ xfb,
                                              const float* __restrict__ cw,
                                              const float* __restrict__ cb,
                                              short* __restrict__ xcb) {
    size_t i = (size_t)blockIdx.x * 256 + threadIdx.x;
    int d = (int)(i % Dn);
    int p = (int)(i / Dn);
    int w = p & 63; p >>= 6;
    int h = p & 63; p >>= 6;
    int b = p;
    float acc = cb[d];
#pragma unroll
    for (int kh = 0; kh < 3; kh++) {
        int hh = h + kh - 1;
        if (hh < 0 || hh >= H_) continue;
#pragma unroll
        for (int kw = 0; kw < 3; kw++) {
            int ww = w + kw - 1;
            if (ww < 0 || ww >= W_) continue;
            acc = fmaf(bf2f(xfb[(((size_t)b * H_ + hh) * W_ + ww) * Dn + d]),
                       cw[d * 9 + kh * 3 + kw], acc);
        }
    }
    float sig = 1.f / (1.f + __expf(-acc));
    xcb[i] = f2bf(acc * sig);
}

// ---------------- per-step delta / e1 helper (branchless) -------------------
__device__ __forceinline__ void delta_e1(float x, float& delta, float& e1) {
    float t = __expf(fminf(x, 80.f));
    float opt = 1.f + t;
    delta = __logf(opt);
    e1 = __builtin_amdgcn_rcpf(opt);
}

__device__ __forceinline__ float dot12t(const float4& a, const float4& b,
                                        const float4& c, const float* w, float bias) {
    float xa = fmaf(a.x, w[0], bias);
    float xb = a.y * w[1];
    float xc = a.z * w[2];
    xa = fmaf(a.w, w[3], xa);
    xb = fmaf(b.x, w[4], xb);
    xc = fmaf(b.y, w[5], xc);
    xa = fmaf(b.z, w[6], xa);
    xb = fmaf(b.w, w[7], xb);
    xc = fmaf(c.x, w[8], xc);
    xa = fmaf(c.y, w[9], xa);
    xb = fmaf(c.z, w[10], xb);
    xc = fmaf(c.w, w[11], xc);
    return (xa + xb) + xc;
}

// ---------------- fused single-pass selective scan (decoupled lookback) -----
// Per block (b,k,chunk c): local scan keeping e1[ts],du[ts] in regs and u in
// LDS; publish compact local (e1p, h[8]); lookback over predecessors with
// inclusive short-circuit; emit y replaying only the h-update.
// Fast path requires A[n] = -(n+1) (true for these inputs); general path
// falls back to serial inclusive-wait (correct, slower, never taken here).
__global__ __launch_bounds__(192, 4) void k_scan(
        const short* __restrict__ xcb, const float* __restrict__ xdbl,
        const float* __restrict__ dtw_all, const float* __restrict__ dtb_all,
        const float* __restrict__ alog, const float* __restrict__ dvec,
        float* __restrict__ e1loc, float* __restrict__ hloc,
        float* __restrict__ hincl, int* flags,
        short* __restrict__ y0, short* __restrict__ y1,
        short* __restrict__ y2, short* __restrict__ y3) {
    const int blk = blockIdx.x;            // ((b*K + k)*NC + c)
    const int c = blk % NC;
    const int k = (blk / NC) % K_;
    const int b = blk / (NC * K_);
    const int d = threadIdx.x;
    const int t0 = c * CS;
    const int stride = ((k & 1) ? 64 : 1) * ((k >= 2) ? -1 : 1);
    const int lm0 = map_t(k, t0);
    short* __restrict__ yk = (k == 0) ? y0 : (k == 1) ? y1 : (k == 2) ? y2 : y3;

    __shared__ float4 sx4[CS][7];          // dt(12)|B(8)|C(8) per step, f32
    __shared__ short u_s[CS][192];         // u passthrough for emission
    const float4* xd4 = reinterpret_cast<const float4*>(xdbl);
    for (int i = d; i < CS * 7; i += 192) {
        int ts = i / 7, q = i % 7;
        sx4[ts][q] = xd4[((size_t)b * L_ + lm0 + ts * stride) * 28 + k * 7 + q];
    }
    __syncthreads();

    float dtw[R_];
#pragma unroll
    for (int r = 0; r < R_; r++) dtw[r] = dtw_all[((size_t)k * Dn + d) * R_ + r];
    const float bias = dtb_all[k * Dn + d];
    const float Dk = dvec[k * Dn + d];
    float Av[Nst];
    bool fast = true;
#pragma unroll
    for (int n = 0; n < Nst; n++) {
        Av[n] = -__expf(alog[((size_t)k * Dn + d) * Nst + n]);
        fast = fast && (fabsf(Av[n] + (float)(n + 1)) < 1e-3f);
    }
    const int fastall = __syncthreads_and((int)fast);   // block-uniform

    float e1a[CS], dua[CS];                // per-step state (registers)
    float h[Nst] = {};
    float e1p = 1.f;
    float Ap[Nst];
#pragma unroll
    for (int n = 0; n < Nst; n++) Ap[n] = 1.f;

    const long stepD = (long)stride * Dn;
    const short* up = xcb + ((size_t)b * L_ + lm0) * Dn + d;
    short us_next = *up;
    if (fastall) {
#pragma unroll
        for (int ts = 0; ts < CS; ts++) {
            short us = us_next;
            u_s[ts][d] = us;
            float u = bf2f(us);
            up += stepD;
            if (ts + 1 < CS) us_next = *up;
            float4 q0 = sx4[ts][0], q1 = sx4[ts][1], q2 = sx4[ts][2];
            float4 qb0 = sx4[ts][3], qb1 = sx4[ts][4];
            float delta, e1; delta_e1(dot12t(q0, q1, q2, dtw, bias), delta, e1);
            float du = delta * u;
            e1a[ts] = e1; dua[ts] = du;
            e1p *= e1;
            float a2 = e1 * e1, a3 = a2 * e1, a4 = a2 * a2;
            float a5 = a4 * e1, a6 = a4 * a2, a7 = a4 * a3, a8 = a4 * a4;
            h[0] = fmaf(e1, h[0], du * qb0.x);
            h[1] = fmaf(a2, h[1], du * qb0.y);
            h[2] = fmaf(a3, h[2], du * qb0.z);
            h[3] = fmaf(a4, h[3], du * qb0.w);
            h[4] = fmaf(a5, h[4], du * qb1.x);
            h[5] = fmaf(a6, h[5], du * qb1.y);
            h[6] = fmaf(a7, h[6], du * qb1.z);
            h[7] = fmaf(a8, h[7], du * qb1.w);
        }
    } else {
#pragma unroll
        for (int ts = 0; ts < CS; ts++) {
            short us = us_next;
            u_s[ts][d] = us;
            float u = bf2f(us);
            up += stepD;
            if (ts + 1 < CS) us_next = *up;
            float4 q0 = sx4[ts][0], q1 = sx4[ts][1], q2 = sx4[ts][2];
            float4 qb0 = sx4[ts][3], qb1 = sx4[ts][4];
            float Bv[Nst] = {qb0.x, qb0.y, qb0.z, qb0.w, qb1.x, qb1.y, qb1.z, qb1.w};
            float delta, e1; delta_e1(dot12t(q0, q1, q2, dtw, bias), delta, e1);
            float du = delta * u;
            e1a[ts] = delta; dua[ts] = du;   // general: store delta
#pragma unroll
            for (int n = 0; n < Nst; n++) {
                float a = __expf(delta * Av[n]);
                Ap[n] *= a;
                h[n] = fmaf(a, h[n], du * Bv[n]);
            }
        }
    }

    // ---- lookback: obtain h_in (state entering this chunk) ----
    const int chain0 = blk - c;
    const size_t rec = ((size_t)blk * 192 + d) * 8;
    float hin[Nst];
    if (c == 0) {
#pragma unroll
        for (int n = 0; n < Nst; n++) hin[n] = 0.f;
    } else if (fastall) {
        // publish local (e1p + h[8]) so successors can progress
        float4* hl4 = reinterpret_cast<float4*>(hloc + rec);
        hl4[0] = make_float4(h[0], h[1], h[2], h[3]);
        hl4[1] = make_float4(h[4], h[5], h[6], h[7]);
        e1loc[(size_t)blk * 192 + d] = e1p;
        __threadfence();
        __syncthreads();
        if (d == 0)
            __hip_atomic_store(&flags[blk], 1, __ATOMIC_RELEASE,
                               __HIP_MEMORY_SCOPE_AGENT);
        // walk predecessors (per-lane; divergence-safe, no barriers inside)
        float Ea = 1.f, ha[Nst];
#pragma unroll
        for (int n = 0; n < Nst; n++) ha[n] = 0.f;
        int j = blk - 1;
        while (true) {
            int f;
            do {
                f = __hip_atomic_load(&flags[j], __ATOMIC_ACQUIRE,
                                      __HIP_MEMORY_SCOPE_AGENT);
                if (f == 0) __builtin_amdgcn_s_sleep(1);
            } while (f == 0);
            size_t prec = ((size_t)j * 192 + d) * 8;
            float E2 = Ea * Ea, E3 = E2 * Ea, E4 = E2 * E2;
            float E5 = E4 * Ea, E6 = E4 * E2, E7 = E4 * E3, E8 = E4 * E4;
            float Ep[Nst] = {Ea, E2, E3, E4, E5, E6, E7, E8};
            if (f == 2) {
                const float4* hi4 = reinterpret_cast<const float4*>(hincl + prec);
                float4 a0 = hi4[0], a1 = hi4[1];
                float hi[Nst] = {a0.x, a0.y, a0.z, a0.w, a1.x, a1.y, a1.z, a1.w};
#pragma unroll
                for (int n = 0; n < Nst; n++) hin[n] = fmaf(Ep[n], hi[n], ha[n]);
                break;
            }
            const float4* hl4r = reinterpret_cast<const float4*>(hloc + prec);
            float4 a0 = hl4r[0], a1 = hl4r[1];
            float hl[Nst] = {a0.x, a0.y, a0.z, a0.w, a1.x, a1.y, a1.z, a1.w};
            float pj = e1loc[(size_t)j * 192 + d];
#pragma unroll
            for (int n = 0; n < Nst; n++) ha[n] = fmaf(Ep[n], hl[n], ha[n]);
            Ea *= pj;
            if (j == chain0) {          // start of chain: h_in of chunk0 is 0
#pragma unroll
                for (int n = 0; n < Nst; n++) hin[n] = ha[n];
                break;
            }
            j--;
        }
    } else {
        // general path: serial wait on predecessor's inclusive
        int f;
        do {
            f = __hip_atomic_load(&flags[blk - 1], __ATOMIC_ACQUIRE,
                                  __HIP_MEMORY_SCOPE_AGENT);
            if (f != 2) __builtin_amdgcn_s_sleep(8);
        } while (f != 2);
        size_t prec = ((size_t)(blk - 1) * 192 + d) * 8;
        const float4* hi4 = reinterpret_cast<const float4*>(hincl + prec);
        float4 a0 = hi4[0], a1 = hi4[1];
        hin[0] = a0.x; hin[1] = a0.y; hin[2] = a0.z; hin[3] = a0.w;
        hin[4] = a1.x; hin[5] = a1.y; hin[6] = a1.z; hin[7] = a1.w;
    }

    // ---- publish inclusive (not needed for last chunk of a chain) ----
    if (c != NC - 1) {
        float hi_[Nst];
        if (fastall) {
            float P2 = e1p * e1p, P3 = P2 * e1p, P4 = P2 * P2;
            float P5 = P4 * e1p, P6 = P4 * P2, P7 = P4 * P3, P8 = P4 * P4;
            float Pp[Nst] = {e1p, P2, P3, P4, P5, P6, P7, P8};
#pragma unroll
            for (int n = 0; n < Nst; n++) hi_[n] = fmaf(Pp[n], hin[n], h[n]);
        } else {
#pragma unroll
            for (int n = 0; n < Nst; n++) hi_[n] = fmaf(Ap[n], hin[n], h[n]);
        }
        float4* hi4w = reinterpret_cast<float4*>(hincl + rec);
        hi4w[0] = make_float4(hi_[0], hi_[1], hi_[2], hi_[3]);
        hi4w[1] = make_float4(hi_[4], hi_[5], hi_[6], hi_[7]);
        __threadfence();
        __syncthreads();
        if (d == 0)
            __hip_atomic_store(&flags[blk], 2, __ATOMIC_RELEASE,
                               __HIP_MEMORY_SCOPE_AGENT);
    }

    // ---- emission: replay h-update with stored e1/du, emit y ----
#pragma unroll
    for (int n = 0; n < Nst; n++) h[n] = hin[n];
    short* yp = yk + ((size_t)b * L_ + lm0) * Dn + d;
    if (fastall) {
#pragma unroll
        for (int ts = 0; ts < CS; ts++) {
            float e1 = e1a[ts], du = dua[ts];
            float4 qb0 = sx4[ts][3], qb1 = sx4[ts][4];
            float4 qc0 = sx4[ts][5], qc1 = sx4[ts][6];
            float a2 = e1 * e1, a3 = a2 * e1, a4 = a2 * a2;
            float a5 = a4 * e1, a6 = a4 * a2, a7 = a4 * a3, a8 = a4 * a4;
            h[0] = fmaf(e1, h[0], du * qb0.x);
            h[1] = fmaf(a2, h[1], du * qb0.y);
            h[2] = fmaf(a3, h[2], du * qb0.z);
            h[3] = fmaf(a4, h[3], du * qb0.w);
            h[4] = fmaf(a5, h[4], du * qb1.x);
            h[5] = fmaf(a6, h[5], du * qb1.y);
            h[6] = fmaf(a7, h[6], du * qb1.z);
            h[7] = fmaf(a8, h[7], du * qb1.w);
            float u = bf2f(u_s[ts][d]);
            float ya = fmaf(h[0], qc0.x, Dk * u);
            float yb = h[4] * qc1.x;
            ya = fmaf(h[1], qc0.y, ya);
            yb = fmaf(h[5], qc1.y, yb);
            ya = fmaf(h[2], qc0.z, ya);
            yb = fmaf(h[6], qc1.z, yb);
            ya = fmaf(h[3], qc0.w, ya);
            yb = fmaf(h[7], qc1.w, yb);
            *yp = f2bf(ya + yb);
            yp += stepD;
        }
    } else {
#pragma unroll
        for (int ts = 0; ts < CS; ts++) {
            float delta = e1a[ts], du = dua[ts];
            float4 qb0 = sx4[ts][3], qb1 = sx4[ts][4];
            float4 qc0 = sx4[ts][5], qc1 = sx4[ts][6];
            float Bv[Nst] = {qb0.x, qb0.y, qb0.z, qb0.w, qb1.x, qb1.y, qb1.z, qb1.w};
            float Cv[Nst] = {qc0.x, qc0.y, qc0.z, qc0.w, qc1.x, qc1.y, qc1.z, qc1.w};
            float u = bf2f(u_s[ts][d]);
            float y = Dk * u;
#pragma unroll
            for (int n = 0; n < Nst; n++) {
                float a = __expf(delta * Av[n]);
                h[n] = fmaf(a, h[n], du * Bv[n]);
                y = fmaf(h[n], Cv[n], y);
            }
            *yp = f2bf(y);
            yp += stepD;
        }
    }
}

// ---------------- merge 4 dirs + LayerNorm(Dn) * SiLU(z) -> bf16 ------------
__global__ __launch_bounds__(256) void k_ln(const short* __restrict__ y0,
                                            const short* __restrict__ y1,
                                            const short* __restrict__ y2,
                                            const short* __restrict__ y3,
                                            const short* __restrict__ zb,
                                            const float* __restrict__ lnw,
                                            const float* __restrict__ lnb,
                                            short* __restrict__ yfin) {
    const int row = blockIdx.x * 4 + (threadIdx.x >> 6);
    const int lane = threadIdx.x & 63;
    const size_t base = (size_t)row * Dn;
    float v[3];
    float s = 0.f, s2 = 0.f;
#pragma unroll
    for (int j = 0; j < 3; j++) {
        size_t idx = base + lane + j * 64;
        v[j] = bf2f(y0[idx]) + bf2f(y1[idx]) + bf2f(y2[idx]) + bf2f(y3[idx]);
        s += v[j];
        s2 = fmaf(v[j], v[j], s2);
    }
#pragma unroll
    for (int o = 1; o < 64; o <<= 1) {
        s += __shfl_xor(s, o);
        s2 += __shfl_xor(s2, o);
    }
    const float inv = 1.f / 192.f;
    float mu = s * inv;
    float var = s2 * inv - mu * mu;
    float rstd = rsqrtf(var + 1e-5f);
#pragma unroll
    for (int j = 0; j < 3; j++) {
        int dd = lane + j * 64;
        size_t idx = base + dd;
        float zz = bf2f(zb[idx]);
        float sig = 1.f / (1.f + __expf(-zz));
        float res = ((v[j] - mu) * rstd * lnw[dd] + lnb[dd]) * (zz * sig);
        yfin[idx] = f2bf(res);
    }
}

// ---------------- launcher ---------------------------------------------------
extern "C" void kernel_launch(void* const* d_in, const int* in_sizes, int n_in,
                              void* d_out, int out_size, void* d_ws, size_t ws_size,
                              hipStream_t stream) {
    const float* x    = (const float*)d_in[0];
    const float* w_in = (const float*)d_in[1];
    const float* cw   = (const float*)d_in[2];
    const float* cb   = (const float*)d_in[3];
    const float* xpw  = (const float*)d_in[4];
    const float* dtw  = (const float*)d_in[5];
    const float* dtb  = (const float*)d_in[6];
    const float* alog = (const float*)d_in[7];
    const float* dvec = (const float*)d_in[8];
    const float* lnw  = (const float*)d_in[9];
    const float* lnb  = (const float*)d_in[10];
    const float* wout = (const float*)d_in[11];
    float* out = (float*)d_out;

    const size_t SH = (size_t)MROWS * Dn;                // 6,291,456 elems

    char* p = (char*)d_ws;
    short* x_bf  = (short*)p; p += SH * 2;               // -> y0 after in_proj
    short* xf_bf = (short*)p; p += SH * 2;               // -> y1 after conv
    short* z_bf  = (short*)p; p += SH * 2;
    short* xc_bf = (short*)p; p += SH * 2;
    float* xdbl  = (float*)p; p += (size_t)MROWS * (K_ * CPROJ) * 4;  // f32
    float* e1loc = (float*)p; p += (size_t)NBLK * 192 * 4;
    float* hloc  = (float*)p; p += (size_t)NBLK * 192 * 8 * 4;  // -> yfin
    float* hincl = (float*)p; p += (size_t)NBLK * 192 * 8 * 4;
    short* y2buf = (short*)p; p += SH * 2;
    short* y3buf = (short*)p; p += SH * 2;
    int*   flags = (int*)p;   p += (size_t)NBLK * 4;
    short* w_bf  = (short*)p;
    // aliases: y0<-x_bf (dead after in_proj), y1<-xf_bf (dead after conv),
    // yfin<-hloc (dead after k_scan; k_ln runs after).
    short* y0 = x_bf;
    short* y1 = xf_bf;
    short* yfin_bf = (short*)hloc;

    // 0. fused converts
    k_cvt<<<(XUNITS + WUNITS + 255) / 256, 256, 0, stream>>>(x, w_in, xpw, wout,
                                                             x_bf, w_bf);
    // 1. in_proj (MFMA) -> xf_bf, z_bf
    k_mgemm_in<<<dim3(MROWS / 128, 6), 256, 0, stream>>>(x_bf, w_bf + WOFF_IN,
                                                         xf_bf, z_bf, C_);
    // 2. depthwise conv 3x3 + SiLU -> xc_bf
    k_conv<<<(int)(SH / 256), 256, 0, stream>>>(xf_bf, cw, cb, xc_bf);
    // 3. x_dbl (all 4 dirs, one MFMA GEMM) -> f32
    k_mgemm_f<<<dim3(MROWS / 128, 2), 256, 0, stream>>>(xc_bf, w_bf + WOFF_XP,
                                                        xdbl, K_ * CPROJ, Dn);
    // 4. fused single-pass selective scan (decoupled lookback)
    hipMemsetAsync(flags, 0, (size_t)NBLK * 4, stream);
    k_scan<<<NBLK, 192, 0, stream>>>(xc_bf, xdbl, dtw, dtb, alog, dvec,
                                     e1loc, hloc, hincl, flags,
                                     y0, y1, y2buf, y3buf);
    // 5. merge + LayerNorm * SiLU(z) -> bf16
    k_ln<<<MROWS / 4, 256, 0, stream>>>(y0, y1, y2buf, y3buf, z_bf, lnw, lnb,
                                        yfin_bf);
    // 6. out_proj (MFMA) -> d_out (f32)
    k_mgemm_f<<<dim3(MROWS / 128, 3), 256, 0, stream>>>(yfin_bf, w_bf + WOFF_OUT,
                                                        out, C_, Dn);
}

// Round 8
// 241.432 us; speedup vs baseline: 13.5710x; 13.5710x over previous
//
#include <hip/hip_runtime.h>
#include <hip/hip_bf16.h>

// ---------------- problem constants (fixed by setup_inputs) ----------------
constexpr int B_  = 8;
constexpr int H_  = 64;
constexpr int W_  = 64;
constexpr int C_  = 192;
constexpr int Dn  = 192;
constexpr int Nst = 8;    // state dim N
constexpr int R_  = 12;
constexpr int K_  = 4;    // directions
constexpr int L_  = H_ * W_;          // 4096
constexpr int CS  = 32;               // scan chunk size
constexpr int NC  = L_ / CS;          // 128 chunks
constexpr int CPROJ = R_ + 2 * Nst;   // 28
constexpr int MROWS = B_ * L_;        // 32768

typedef __attribute__((ext_vector_type(8))) short short8v;
typedef __attribute__((ext_vector_type(4))) float f32x4;
typedef __attribute__((ext_vector_type(2))) float f32x2;

// t -> spatial position for direction k (verified round 0).
// Within a chunk: lm = map_t(k,t0) + ts*stride (no wrap since CS | 64).
__device__ __forceinline__ int map_t(int k, int t) {
    int tt = (k >= 2) ? (L_ - 1 - t) : t;
    if (k & 1) tt = (tt & 63) * 64 + (tt >> 6);
    return tt;
}

__device__ __forceinline__ short f2bf(float f) {   // round-to-nearest-even
    unsigned u = __float_as_uint(f);
    u += 0x7FFFu + ((u >> 16) & 1u);
    return (short)(u >> 16);
}
__device__ __forceinline__ float bf2f(short s) {
    return __uint_as_float(((unsigned)(unsigned short)s) << 16);
}

// packed fp32 helpers (lower to v_pk_fma_f32 / v_pk_mul_f32 on gfx950)
__device__ __forceinline__ f32x2 mk2(float a, float b) { f32x2 v; v.x = a; v.y = b; return v; }
__device__ __forceinline__ f32x2 lo2(float4 v) { return mk2(v.x, v.y); }
__device__ __forceinline__ f32x2 hi2(float4 v) { return mk2(v.z, v.w); }
__device__ __forceinline__ f32x2 pkfma(f32x2 a, f32x2 b, f32x2 c) {
    return __builtin_elementwise_fma(a, b, c);
}

// ---------------- fused f32 -> bf16 convert (x and all weights) -------------
constexpr int WOFF_IN  = 0;               // w_in  (384x192)
constexpr int WOFF_XP  = 73728;           // xpw   (112x192)
constexpr int WOFF_OUT = 95232;           // wout  (192x192)
constexpr int WTOTAL   = 132096;
constexpr int XUNITS   = MROWS * Dn / 8;  // 786432
constexpr int WUNITS   = WTOTAL / 8;      // 16512
__global__ __launch_bounds__(256) void k_cvt(const float* __restrict__ x,
                                             const float* __restrict__ w_in,
                                             const float* __restrict__ xpw,
                                             const float* __restrict__ wout,
                                             short* __restrict__ x_bf,
                                             short* __restrict__ w_bf) {
    int g = blockIdx.x * 256 + threadIdx.x;
    const float* src;
    short* dst;
    int off;
    if (g < XUNITS) { src = x; dst = x_bf; off = g * 8; }
    else {
        g -= XUNITS;
        if (g >= WUNITS) return;
        int base = g * 8;
        dst = w_bf; off = base;
        if (base < WOFF_XP)       { src = w_in; }
        else if (base < WOFF_OUT) { src = xpw;  src -= WOFF_XP; }
        else                      { src = wout; src -= WOFF_OUT; }
    }
    float4 a = *reinterpret_cast<const float4*>(src + off);
    float4 b = *reinterpret_cast<const float4*>(src + off + 4);
    short8v v = {f2bf(a.x), f2bf(a.y), f2bf(a.z), f2bf(a.w),
                 f2bf(b.x), f2bf(b.y), f2bf(b.z), f2bf(b.w)};
    *reinterpret_cast<short8v*>(dst + off) = v;
}

// ---------------- bf16 MFMA GEMM cores --------------------------------------
__device__ __forceinline__ void mgemm_core(const short* __restrict__ A,
                                           const short* __restrict__ Wb,
                                           f32x4 (&acc)[4][2],
                                           int mrow, int ncol, int Nact, int K) {
    const int lane = threadIdx.x & 63;
    const int koff = (lane >> 4) * 8;
    for (int k0 = 0; k0 < K; k0 += 32) {
        short8v af[4], bfr[2];
#pragma unroll
        for (int mf = 0; mf < 4; mf++)
            af[mf] = *reinterpret_cast<const short8v*>(
                A + (size_t)(mrow + mf * 16) * K + k0 + koff);
#pragma unroll
        for (int nf = 0; nf < 2; nf++) {
            int r = ncol + nf * 16;
            short8v z = {0, 0, 0, 0, 0, 0, 0, 0};
            bfr[nf] = (r < Nact)
                ? *reinterpret_cast<const short8v*>(Wb + (size_t)r * K + k0 + koff)
                : z;
        }
#pragma unroll
        for (int mf = 0; mf < 4; mf++)
#pragma unroll
            for (int nf = 0; nf < 2; nf++)
                acc[mf][nf] = __builtin_amdgcn_mfma_f32_16x16x32_bf16(
                    af[mf], bfr[nf], acc[mf][nf], 0, 0, 0);
    }
}

// f32-output GEMM (x_proj, out_proj)
__global__ __launch_bounds__(256) void k_mgemm_f(const short* __restrict__ A,
                                                 const short* __restrict__ Wb,
                                                 float* __restrict__ out0,
                                                 int Nact, int K) {
    const int m0 = blockIdx.x * 128, n0 = blockIdx.y * 64;
    const int wid = threadIdx.x >> 6, lane = threadIdx.x & 63;
    const int wm = wid >> 1, wn = wid & 1;
    f32x4 acc[4][2] = {};
    mgemm_core(A, Wb, acc, m0 + wm * 64 + (lane & 15), n0 + wn * 32 + (lane & 15),
               Nact, K);
    const int prow = (lane >> 4) * 4, pcol = lane & 15;
#pragma unroll
    for (int mf = 0; mf < 4; mf++) {
        int mbase = m0 + wm * 64 + mf * 16 + prow;
#pragma unroll
        for (int nf = 0; nf < 2; nf++) {
            int n = n0 + wn * 32 + nf * 16 + pcol;
            if (n >= Nact) continue;
#pragma unroll
            for (int r = 0; r < 4; r++)
                out0[(size_t)(mbase + r) * Nact + n] = acc[mf][nf][r];
        }
    }
}

// in_proj: split bf16 outputs (xf | z), each ldc=192
__global__ __launch_bounds__(256) void k_mgemm_in(const short* __restrict__ A,
                                                  const short* __restrict__ Wb,
                                                  short* __restrict__ xf_bf,
                                                  short* __restrict__ z_bf,
                                                  int K) {
    const int m0 = blockIdx.x * 128, n0 = blockIdx.y * 64;
    const int wid = threadIdx.x >> 6, lane = threadIdx.x & 63;
    const int wm = wid >> 1, wn = wid & 1;
    f32x4 acc[4][2] = {};
    mgemm_core(A, Wb, acc, m0 + wm * 64 + (lane & 15), n0 + wn * 32 + (lane & 15),
               384, K);
    const int prow = (lane >> 4) * 4, pcol = lane & 15;
#pragma unroll
    for (int mf = 0; mf < 4; mf++) {
        int mbase = m0 + wm * 64 + mf * 16 + prow;
#pragma unroll
        for (int nf = 0; nf < 2; nf++) {
            int n = n0 + wn * 32 + nf * 16 + pcol;
#pragma unroll
            for (int r = 0; r < 4; r++) {
                int m = mbase + r;
                if (n < 192) xf_bf[(size_t)m * 192 + n] = f2bf(acc[mf][nf][r]);
                else         z_bf[(size_t)m * 192 + (n - 192)] = f2bf(acc[mf][nf][r]);
            }
        }
    }
}

// ---------------- depthwise 3x3 conv + bias + SiLU (bf16 in/out) ------------
__global__ __launch_bounds__(256) void k_conv(const short* __restrict__ xfb,
                                              const float* __restrict__ cw,
                                              const float* __restrict__ cb,
                                              short* __restrict__ xcb) {
    size_t i = (size_t)blockIdx.x * 256 + threadIdx.x;
    int d = (int)(i % Dn);
    int p = (int)(i / Dn);
    int w = p & 63; p >>= 6;
    int h = p & 63; p >>= 6;
    int b = p;
    float acc = cb[d];
#pragma unroll
    for (int kh = 0; kh < 3; kh++) {
        int hh = h + kh - 1;
        if (hh < 0 || hh >= H_) continue;
#pragma unroll
        for (int kw = 0; kw < 3; kw++) {
            int ww = w + kw - 1;
            if (ww < 0 || ww >= W_) continue;
            acc = fmaf(bf2f(xfb[(((size_t)b * H_ + hh) * W_ + ww) * Dn + d]),
                       cw[d * 9 + kh * 3 + kw], acc);
        }
    }
    float sig = 1.f / (1.f + __expf(-acc));
    xcb[i] = f2bf(acc * sig);
}

// ---------------- per-step delta / e1 helper (branchless) -------------------
__device__ __forceinline__ void delta_e1(float x, float& delta, float& e1) {
    float t = __expf(fminf(x, 80.f));
    float opt = 1.f + t;
    delta = __logf(opt);
    e1 = __builtin_amdgcn_rcpf(opt);
}

// packed 12-term dot (6 pk_fma), bias folded in
__device__ __forceinline__ float dot12p(const float4& q0, const float4& q1,
                                        const float4& q2, const f32x2* w2,
                                        float bias) {
    f32x2 acc = mk2(bias, 0.f);
    acc = pkfma(lo2(q0), w2[0], acc);
    acc = pkfma(hi2(q0), w2[1], acc);
    acc = pkfma(lo2(q1), w2[2], acc);
    acc = pkfma(hi2(q1), w2[3], acc);
    acc = pkfma(lo2(q2), w2[4], acc);
    acc = pkfma(hi2(q2), w2[5], acc);
    return acc.x + acc.y;
}

// scalar 12-term dot (general path)
__device__ __forceinline__ float dot12(const float4& a, const float4& b,
                                       const float4& c, const float* w, float x) {
    x = fmaf(a.x, w[0], x);  x = fmaf(a.y, w[1], x);
    x = fmaf(a.z, w[2], x);  x = fmaf(a.w, w[3], x);
    x = fmaf(b.x, w[4], x);  x = fmaf(b.y, w[5], x);
    x = fmaf(b.z, w[6], x);  x = fmaf(b.w, w[7], x);
    x = fmaf(c.x, w[8], x);  x = fmaf(c.y, w[9], x);
    x = fmaf(c.z, w[10], x); x = fmaf(c.w, w[11], x);
    return x;
}

// ---------------- scan phase 1: per-chunk (prod(a), h_partial) --------------
// LDS holds per-step [dt(12) | B(8)] = 5 float4 (C not consumed here).
__global__ __launch_bounds__(192, 8) void k_scan1(const short* __restrict__ xcb,
                                               const float* __restrict__ xdbl,
                                               const float* __restrict__ dtw_all,
                                               const float* __restrict__ dtb_all,
                                               const float* __restrict__ alog,
                                               float* __restrict__ Aprod,
                                               float* __restrict__ hpart) {
    const int blk = blockIdx.x;            // ((b*K + k)*NC + c)
    const int c = blk % NC;
    const int k = (blk / NC) % K_;
    const int b = blk / (NC * K_);
    const int d = threadIdx.x;
    const int t0 = c * CS;
    const int stride = ((k & 1) ? 64 : 1) * ((k >= 2) ? -1 : 1);
    const int lm0 = map_t(k, t0);

    __shared__ float4 sx4[CS][5];
    const float4* xd4 = reinterpret_cast<const float4*>(xdbl);
    for (int i = d; i < CS * 5; i += 192) {
        int ts = i / 5, q = i % 5;
        sx4[ts][q] = xd4[((size_t)b * L_ + lm0 + ts * stride) * 28 + k * 7 + q];
    }
    __syncthreads();

    float dtw[R_];
#pragma unroll
    for (int r = 0; r < R_; r++) dtw[r] = dtw_all[((size_t)k * Dn + d) * R_ + r];
    f32x2 w2[6];
#pragma unroll
    for (int r = 0; r < 6; r++) w2[r] = mk2(dtw[2 * r], dtw[2 * r + 1]);
    const float bias = dtb_all[k * Dn + d];
    float Av[Nst];
    bool fast = true;
#pragma unroll
    for (int n = 0; n < Nst; n++) {
        Av[n] = -__expf(alog[((size_t)k * Dn + d) * Nst + n]);
        fast = fast && (fabsf(Av[n] + (float)(n + 1)) < 1e-3f);
    }

    float e1p = 1.f;
    const long stepD = (long)stride * Dn;
    const short* up = xcb + ((size_t)b * L_ + lm0) * Dn + d;
    float u_next = bf2f(*up);
    size_t base = ((((size_t)(b * K_ + k) * NC + c) * Dn + d)) * Nst;

    if (fast) {
        f32x2 h01 = mk2(0.f, 0.f), h23 = h01, h45 = h01, h67 = h01;
        for (int ts = 0; ts < CS; ts++) {
            float u = u_next;
            up += stepD;
            if (ts + 1 < CS) u_next = bf2f(*up);
            float4 q0 = sx4[ts][0], q1 = sx4[ts][1], q2 = sx4[ts][2];
            float4 qb0 = sx4[ts][3], qb1 = sx4[ts][4];
            float delta, e1; delta_e1(dot12p(q0, q1, q2, w2, bias), delta, e1);
            float du = delta * u;
            e1p *= e1;
            float a2 = e1 * e1;
            f32x2 p12 = mk2(e1, a2);
            f32x2 a22 = mk2(a2, a2);
            f32x2 p34 = a22 * p12;
            f32x2 a44 = mk2(p34.y, p34.y);
            f32x2 p56 = a44 * p12;
            f32x2 p78 = a44 * p34;
            f32x2 du2 = mk2(du, du);
            h01 = pkfma(p12, h01, du2 * lo2(qb0));
            h23 = pkfma(p34, h23, du2 * hi2(qb0));
            h45 = pkfma(p56, h45, du2 * lo2(qb1));
            h67 = pkfma(p78, h67, du2 * hi2(qb1));
        }
        float p2 = e1p * e1p, p3 = p2 * e1p, p4 = p2 * p2;
        float4* ap4 = reinterpret_cast<float4*>(Aprod + base);
        ap4[0] = make_float4(e1p, p2, p3, p4);
        ap4[1] = make_float4(p4 * e1p, p4 * p2, p4 * p3, p4 * p4);
        float4* hp4 = reinterpret_cast<float4*>(hpart + base);
        hp4[0] = make_float4(h01.x, h01.y, h23.x, h23.y);
        hp4[1] = make_float4(h45.x, h45.y, h67.x, h67.y);
    } else {
        float h[Nst] = {};
        float Ap[Nst];
#pragma unroll
        for (int n = 0; n < Nst; n++) Ap[n] = 1.f;
        for (int ts = 0; ts < CS; ts++) {
            float u = u_next;
            up += stepD;
            if (ts + 1 < CS) u_next = bf2f(*up);
            float4 q0 = sx4[ts][0], q1 = sx4[ts][1], q2 = sx4[ts][2];
            float4 qb0 = sx4[ts][3], qb1 = sx4[ts][4];
            float Bv[Nst] = {qb0.x, qb0.y, qb0.z, qb0.w, qb1.x, qb1.y, qb1.z, qb1.w};
            float delta, e1; delta_e1(dot12(q0, q1, q2, dtw, bias), delta, e1);
            float du = delta * u;
#pragma unroll
            for (int n = 0; n < Nst; n++) {
                float a = __expf(delta * Av[n]);
                Ap[n] *= a;
                h[n] = fmaf(a, h[n], du * Bv[n]);
            }
        }
#pragma unroll
        for (int n = 0; n < Nst; n++) { Aprod[base + n] = Ap[n]; hpart[base + n] = h[n]; }
    }
}

// ---------------- scan phase 2: chunk-level recurrence -----------------------
__global__ __launch_bounds__(256) void k_scan2(const float* __restrict__ Aprod,
                                               const float* __restrict__ hpart,
                                               float* __restrict__ hin) {
    int idx = blockIdx.x * 256 + threadIdx.x;   // B*K*Dn*Nst = 49152
    int dn = idx % (Dn * Nst);
    int bk = idx / (Dn * Nst);
    size_t stride = (size_t)Dn * Nst;
    size_t base = (size_t)bk * NC * stride + dn;
    float h = 0.f;
    for (int cc = 0; cc < NC; cc++) {
        size_t s = base + (size_t)cc * stride;
        hin[s] = h;
        h = fmaf(Aprod[s], h, hpart[s]);
    }
}

// ---------------- scan phase 3: recompute with h_in, emit y (plain store) ---
// LDS holds per-step [dt(12) | B(8) | C(8)] = 7 float4.
__global__ __launch_bounds__(192, 8) void k_scan3(const short* __restrict__ xcb,
                                               const float* __restrict__ xdbl,
                                               const float* __restrict__ dtw_all,
                                               const float* __restrict__ dtb_all,
                                               const float* __restrict__ alog,
                                               const float* __restrict__ dvec,
                                               const float* __restrict__ hin,
                                               short* __restrict__ y0,
                                               short* __restrict__ y1,
                                               short* __restrict__ y2,
                                               short* __restrict__ y3) {
    const int blk = blockIdx.x;
    const int c = blk % NC;
    const int k = (blk / NC) % K_;
    const int b = blk / (NC * K_);
    const int d = threadIdx.x;
    const int t0 = c * CS;
    const int stride = ((k & 1) ? 64 : 1) * ((k >= 2) ? -1 : 1);
    const int lm0 = map_t(k, t0);
    short* __restrict__ yk = (k == 0) ? y0 : (k == 1) ? y1 : (k == 2) ? y2 : y3;

    __shared__ float4 sx4[CS][7];
    const float4* xd4 = reinterpret_cast<const float4*>(xdbl);
    for (int i = d; i < CS * 7; i += 192) {
        int ts = i / 7, q = i % 7;
        sx4[ts][q] = xd4[((size_t)b * L_ + lm0 + ts * stride) * 28 + k * 7 + q];
    }
    __syncthreads();

    float dtw[R_];
#pragma unroll
    for (int r = 0; r < R_; r++) dtw[r] = dtw_all[((size_t)k * Dn + d) * R_ + r];
    f32x2 w2[6];
#pragma unroll
    for (int r = 0; r < 6; r++) w2[r] = mk2(dtw[2 * r], dtw[2 * r + 1]);
    const float bias = dtb_all[k * Dn + d];
    const float Dk = dvec[k * Dn + d];
    float Av[Nst];
    bool fast = true;
#pragma unroll
    for (int n = 0; n < Nst; n++) {
        Av[n] = -__expf(alog[((size_t)k * Dn + d) * Nst + n]);
        fast = fast && (fabsf(Av[n] + (float)(n + 1)) < 1e-3f);
    }

    size_t hbase = ((((size_t)(b * K_ + k) * NC + c) * Dn + d)) * Nst;
    const long stepD = (long)stride * Dn;
    const short* up = xcb + ((size_t)b * L_ + lm0) * Dn + d;
    short* yp = yk + ((size_t)b * L_ + lm0) * Dn + d;
    float u_next = bf2f(*up);

    if (fast) {
        const float4* hi4 = reinterpret_cast<const float4*>(hin + hbase);
        float4 ha = hi4[0], hb = hi4[1];
        f32x2 h01 = lo2(ha), h23 = hi2(ha), h45 = lo2(hb), h67 = hi2(hb);
        for (int ts = 0; ts < CS; ts++) {
            float u = u_next;
            up += stepD;
            if (ts + 1 < CS) u_next = bf2f(*up);
            float4 q0 = sx4[ts][0], q1 = sx4[ts][1], q2 = sx4[ts][2];
            float4 qb0 = sx4[ts][3], qb1 = sx4[ts][4];
            float4 qc0 = sx4[ts][5], qc1 = sx4[ts][6];
            float delta, e1; delta_e1(dot12p(q0, q1, q2, w2, bias), delta, e1);
            float du = delta * u;
            float a2 = e1 * e1;
            f32x2 p12 = mk2(e1, a2);
            f32x2 a22 = mk2(a2, a2);
            f32x2 p34 = a22 * p12;
            f32x2 a44 = mk2(p34.y, p34.y);
            f32x2 p56 = a44 * p12;
            f32x2 p78 = a44 * p34;
            f32x2 du2 = mk2(du, du);
            h01 = pkfma(p12, h01, du2 * lo2(qb0));
            h23 = pkfma(p34, h23, du2 * hi2(qb0));
            h45 = pkfma(p56, h45, du2 * lo2(qb1));
            h67 = pkfma(p78, h67, du2 * hi2(qb1));
            f32x2 yacc = mk2(Dk * u, 0.f);
            yacc = pkfma(h01, lo2(qc0), yacc);
            yacc = pkfma(h23, hi2(qc0), yacc);
            yacc = pkfma(h45, lo2(qc1), yacc);
            yacc = pkfma(h67, hi2(qc1), yacc);
            *yp = f2bf(yacc.x + yacc.y);
            yp += stepD;
        }
    } else {
        float h[Nst];
#pragma unroll
        for (int n = 0; n < Nst; n++) h[n] = hin[hbase + n];
        for (int ts = 0; ts < CS; ts++) {
            float u = u_next;
            up += stepD;
            if (ts + 1 < CS) u_next = bf2f(*up);
            float4 q0 = sx4[ts][0], q1 = sx4[ts][1], q2 = sx4[ts][2];
            float4 qb0 = sx4[ts][3], qb1 = sx4[ts][4];
            float4 qc0 = sx4[ts][5], qc1 = sx4[ts][6];
            float Bv[Nst] = {qb0.x, qb0.y, qb0.z, qb0.w, qb1.x, qb1.y, qb1.z, qb1.w};
            float Cv[Nst] = {qc0.x, qc0.y, qc0.z, qc0.w, qc1.x, qc1.y, qc1.z, qc1.w};
            float delta, e1; delta_e1(dot12(q0, q1, q2, dtw, bias), delta, e1);
            float du = delta * u;
            float y = Dk * u;
#pragma unroll
            for (int n = 0; n < Nst; n++) {
                float a = __expf(delta * Av[n]);
                h[n] = fmaf(a, h[n], du * Bv[n]);
                y = fmaf(h[n], Cv[n], y);
            }
            *yp = f2bf(y);
            yp += stepD;
        }
    }
}

// ---------------- merge 4 dirs + LayerNorm(Dn) * SiLU(z) -> bf16 ------------
__global__ __launch_bounds__(256) void k_ln(const short* __restrict__ y0,
                                            const short* __restrict__ y1,
                                            const short* __restrict__ y2,
                                            const short* __restrict__ y3,
                                            const short* __restrict__ zb,
                                            const float* __restrict__ lnw,
                                            const float* __restrict__ lnb,
                                            short* __restrict__ yfin) {
    const int row = blockIdx.x * 4 + (threadIdx.x >> 6);
    const int lane = threadIdx.x & 63;
    const size_t base = (size_t)row * Dn;
    float v[3];
    float s = 0.f, s2 = 0.f;
#pragma unroll
    for (int j = 0; j < 3; j++) {
        size_t idx = base + lane + j * 64;
        v[j] = bf2f(y0[idx]) + bf2f(y1[idx]) + bf2f(y2[idx]) + bf2f(y3[idx]);
        s += v[j];
        s2 = fmaf(v[j], v[j], s2);
    }
#pragma unroll
    for (int o = 1; o < 64; o <<= 1) {
        s += __shfl_xor(s, o);
        s2 += __shfl_xor(s2, o);
    }
    const float inv = 1.f / 192.f;
    float mu = s * inv;
    float var = s2 * inv - mu * mu;
    float rstd = rsqrtf(var + 1e-5f);
#pragma unroll
    for (int j = 0; j < 3; j++) {
        int dd = lane + j * 64;
        size_t idx = base + dd;
        float zz = bf2f(zb[idx]);
        float sig = 1.f / (1.f + __expf(-zz));
        float res = ((v[j] - mu) * rstd * lnw[dd] + lnb[dd]) * (zz * sig);
        yfin[idx] = f2bf(res);
    }
}

// ---------------- launcher ---------------------------------------------------
extern "C" void kernel_launch(void* const* d_in, const int* in_sizes, int n_in,
                              void* d_out, int out_size, void* d_ws, size_t ws_size,
                              hipStream_t stream) {
    const float* x    = (const float*)d_in[0];
    const float* w_in = (const float*)d_in[1];
    const float* cw   = (const float*)d_in[2];
    const float* cb   = (const float*)d_in[3];
    const float* xpw  = (const float*)d_in[4];
    const float* dtw  = (const float*)d_in[5];
    const float* dtb  = (const float*)d_in[6];
    const float* alog = (const float*)d_in[7];
    const float* dvec = (const float*)d_in[8];
    const float* lnw  = (const float*)d_in[9];
    const float* lnb  = (const float*)d_in[10];
    const float* wout = (const float*)d_in[11];
    float* out = (float*)d_out;

    const size_t SH  = (size_t)MROWS * Dn;               // 6,291,456 elems
    const size_t SCN = (size_t)B_ * K_ * NC * Dn * Nst;  // 6,291,456 elems

    char* p = (char*)d_ws;
    short* x_bf  = (short*)p; p += SH * 2;               // region0 -> y0
    short* xf_bf = (short*)p; p += SH * 2;               // region1 -> y1
    short* z_bf  = (short*)p; p += SH * 2;               // region2
    short* xc_bf = (short*)p; p += SH * 2;               // region3
    float* xdbl  = (float*)p; p += (size_t)MROWS * (K_ * CPROJ) * 4;
    float* Aprod = (float*)p; p += SCN * 4;              // region5 -> y2
    float* hpart = (float*)p; p += SCN * 4;              // region6 -> y3
    float* hin   = (float*)p; p += SCN * 4;              // region7 -> yfin
    short* w_bf  = (short*)p;
    // aliases (lifetimes): y0<-x_bf (dead after in_proj), y1<-xf_bf (dead after
    // conv), y2<-Aprod, y3<-hpart (dead after scan2), yfin<-hin (dead after
    // scan3; k_ln runs after scan3).
    short* y0 = x_bf;
    short* y1 = xf_bf;
    short* y2 = (short*)Aprod;
    short* y3 = (short*)hpart;
    short* yfin_bf = (short*)hin;

    // 0. fused converts
    k_cvt<<<(XUNITS + WUNITS + 255) / 256, 256, 0, stream>>>(x, w_in, xpw, wout,
                                                             x_bf, w_bf);
    // 1. in_proj (MFMA) -> xf_bf, z_bf
    k_mgemm_in<<<dim3(MROWS / 128, 6), 256, 0, stream>>>(x_bf, w_bf + WOFF_IN,
                                                         xf_bf, z_bf, C_);
    // 2. depthwise conv 3x3 + SiLU -> xc_bf
    k_conv<<<(int)(SH / 256), 256, 0, stream>>>(xf_bf, cw, cb, xc_bf);
    // 3. x_dbl (all 4 dirs, one MFMA GEMM) -> f32
    k_mgemm_f<<<dim3(MROWS / 128, 2), 256, 0, stream>>>(xc_bf, w_bf + WOFF_XP,
                                                        xdbl, K_ * CPROJ, Dn);
    // 4-6. chunked parallel selective scan (CS=32, packed fp32 math)
    k_scan1<<<B_ * K_ * NC, 192, 0, stream>>>(xc_bf, xdbl, dtw, dtb, alog, Aprod, hpart);
    k_scan2<<<(B_ * K_ * Dn * Nst) / 256, 256, 0, stream>>>(Aprod, hpart, hin);
    k_scan3<<<B_ * K_ * NC, 192, 0, stream>>>(xc_bf, xdbl, dtw, dtb, alog, dvec,
                                              hin, y0, y1, y2, y3);
    // 7. merge + LayerNorm * SiLU(z) -> bf16
    k_ln<<<MROWS / 4, 256, 0, stream>>>(y0, y1, y2, y3, z_bf, lnw, lnb, yfin_bf);
    // 8. out_proj (MFMA) -> d_out (f32)
    k_mgemm_f<<<dim3(MROWS / 128, 3), 256, 0, stream>>>(yfin_bf, w_bf + WOFF_OUT,
                                                        out, C_, Dn);
}

// Round 9
// 239.350 us; speedup vs baseline: 13.6891x; 1.0087x over previous
//
#include <hip/hip_runtime.h>
#include <hip/hip_bf16.h>

// ---------------- problem constants (fixed by setup_inputs) ----------------
constexpr int B_  = 8;
constexpr int H_  = 64;
constexpr int W_  = 64;
constexpr int C_  = 192;
constexpr int Dn  = 192;
constexpr int Nst = 8;    // state dim N
constexpr int R_  = 12;
constexpr int K_  = 4;    // directions
constexpr int L_  = H_ * W_;          // 4096
constexpr int CS  = 32;               // scan chunk size
constexpr int GS  = 8;                // pipeline group size (CS % GS == 0)
constexpr int NC  = L_ / CS;          // 128 chunks
constexpr int CPROJ = R_ + 2 * Nst;   // 28
constexpr int MROWS = B_ * L_;        // 32768

typedef __attribute__((ext_vector_type(8))) short short8v;
typedef __attribute__((ext_vector_type(4))) float f32x4;
typedef __attribute__((ext_vector_type(2))) float f32x2;

// t -> spatial position for direction k (verified round 0).
// Within a chunk: lm = map_t(k,t0) + ts*stride (no wrap since CS | 64).
__device__ __forceinline__ int map_t(int k, int t) {
    int tt = (k >= 2) ? (L_ - 1 - t) : t;
    if (k & 1) tt = (tt & 63) * 64 + (tt >> 6);
    return tt;
}

__device__ __forceinline__ short f2bf(float f) {   // round-to-nearest-even
    unsigned u = __float_as_uint(f);
    u += 0x7FFFu + ((u >> 16) & 1u);
    return (short)(u >> 16);
}
__device__ __forceinline__ float bf2f(short s) {
    return __uint_as_float(((unsigned)(unsigned short)s) << 16);
}

// packed fp32 helpers (v_pk_fma_f32 / v_pk_mul_f32 on gfx950)
__device__ __forceinline__ f32x2 mk2(float a, float b) { f32x2 v; v.x = a; v.y = b; return v; }
__device__ __forceinline__ f32x2 lo2(float4 v) { return mk2(v.x, v.y); }
__device__ __forceinline__ f32x2 hi2(float4 v) { return mk2(v.z, v.w); }
__device__ __forceinline__ f32x2 pkfma(f32x2 a, f32x2 b, f32x2 c) {
    return __builtin_elementwise_fma(a, b, c);
}

// ---------------- fused f32 -> bf16 convert (x and all weights) -------------
constexpr int WOFF_IN  = 0;               // w_in  (384x192)
constexpr int WOFF_XP  = 73728;           // xpw   (112x192)
constexpr int WOFF_OUT = 95232;           // wout  (192x192)
constexpr int WTOTAL   = 132096;
constexpr int XUNITS   = MROWS * Dn / 8;  // 786432
constexpr int WUNITS   = WTOTAL / 8;      // 16512
__global__ __launch_bounds__(256) void k_cvt(const float* __restrict__ x,
                                             const float* __restrict__ w_in,
                                             const float* __restrict__ xpw,
                                             const float* __restrict__ wout,
                                             short* __restrict__ x_bf,
                                             short* __restrict__ w_bf) {
    int g = blockIdx.x * 256 + threadIdx.x;
    const float* src;
    short* dst;
    int off;
    if (g < XUNITS) { src = x; dst = x_bf; off = g * 8; }
    else {
        g -= XUNITS;
        if (g >= WUNITS) return;
        int base = g * 8;
        dst = w_bf; off = base;
        if (base < WOFF_XP)       { src = w_in; }
        else if (base < WOFF_OUT) { src = xpw;  src -= WOFF_XP; }
        else                      { src = wout; src -= WOFF_OUT; }
    }
    float4 a = *reinterpret_cast<const float4*>(src + off);
    float4 b = *reinterpret_cast<const float4*>(src + off + 4);
    short8v v = {f2bf(a.x), f2bf(a.y), f2bf(a.z), f2bf(a.w),
                 f2bf(b.x), f2bf(b.y), f2bf(b.z), f2bf(b.w)};
    *reinterpret_cast<short8v*>(dst + off) = v;
}

// ---------------- bf16 MFMA GEMM cores --------------------------------------
__device__ __forceinline__ void mgemm_core(const short* __restrict__ A,
                                           const short* __restrict__ Wb,
                                           f32x4 (&acc)[4][2],
                                           int mrow, int ncol, int Nact, int K) {
    const int lane = threadIdx.x & 63;
    const int koff = (lane >> 4) * 8;
    for (int k0 = 0; k0 < K; k0 += 32) {
        short8v af[4], bfr[2];
#pragma unroll
        for (int mf = 0; mf < 4; mf++)
            af[mf] = *reinterpret_cast<const short8v*>(
                A + (size_t)(mrow + mf * 16) * K + k0 + koff);
#pragma unroll
        for (int nf = 0; nf < 2; nf++) {
            int r = ncol + nf * 16;
            short8v z = {0, 0, 0, 0, 0, 0, 0, 0};
            bfr[nf] = (r < Nact)
                ? *reinterpret_cast<const short8v*>(Wb + (size_t)r * K + k0 + koff)
                : z;
        }
#pragma unroll
        for (int mf = 0; mf < 4; mf++)
#pragma unroll
            for (int nf = 0; nf < 2; nf++)
                acc[mf][nf] = __builtin_amdgcn_mfma_f32_16x16x32_bf16(
                    af[mf], bfr[nf], acc[mf][nf], 0, 0, 0);
    }
}

// f32-output GEMM (x_proj, out_proj)
__global__ __launch_bounds__(256) void k_mgemm_f(const short* __restrict__ A,
                                                 const short* __restrict__ Wb,
                                                 float* __restrict__ out0,
                                                 int Nact, int K) {
    const int m0 = blockIdx.x * 128, n0 = blockIdx.y * 64;
    const int wid = threadIdx.x >> 6, lane = threadIdx.x & 63;
    const int wm = wid >> 1, wn = wid & 1;
    f32x4 acc[4][2] = {};
    mgemm_core(A, Wb, acc, m0 + wm * 64 + (lane & 15), n0 + wn * 32 + (lane & 15),
               Nact, K);
    const int prow = (lane >> 4) * 4, pcol = lane & 15;
#pragma unroll
    for (int mf = 0; mf < 4; mf++) {
        int mbase = m0 + wm * 64 + mf * 16 + prow;
#pragma unroll
        for (int nf = 0; nf < 2; nf++) {
            int n = n0 + wn * 32 + nf * 16 + pcol;
            if (n >= Nact) continue;
#pragma unroll
            for (int r = 0; r < 4; r++)
                out0[(size_t)(mbase + r) * Nact + n] = acc[mf][nf][r];
        }
    }
}

// in_proj: split bf16 outputs (xf | z), each ldc=192
__global__ __launch_bounds__(256) void k_mgemm_in(const short* __restrict__ A,
                                                  const short* __restrict__ Wb,
                                                  short* __restrict__ xf_bf,
                                                  short* __restrict__ z_bf,
                                                  int K) {
    const int m0 = blockIdx.x * 128, n0 = blockIdx.y * 64;
    const int wid = threadIdx.x >> 6, lane = threadIdx.x & 63;
    const int wm = wid >> 1, wn = wid & 1;
    f32x4 acc[4][2] = {};
    mgemm_core(A, Wb, acc, m0 + wm * 64 + (lane & 15), n0 + wn * 32 + (lane & 15),
               384, K);
    const int prow = (lane >> 4) * 4, pcol = lane & 15;
#pragma unroll
    for (int mf = 0; mf < 4; mf++) {
        int mbase = m0 + wm * 64 + mf * 16 + prow;
#pragma unroll
        for (int nf = 0; nf < 2; nf++) {
            int n = n0 + wn * 32 + nf * 16 + pcol;
#pragma unroll
            for (int r = 0; r < 4; r++) {
                int m = mbase + r;
                if (n < 192) xf_bf[(size_t)m * 192 + n] = f2bf(acc[mf][nf][r]);
                else         z_bf[(size_t)m * 192 + (n - 192)] = f2bf(acc[mf][nf][r]);
            }
        }
    }
}

// ---------------- depthwise 3x3 conv + bias + SiLU (bf16 in/out) ------------
__global__ __launch_bounds__(256) void k_conv(const short* __restrict__ xfb,
                                              const float* __restrict__ cw,
                                              const float* __restrict__ cb,
                                              short* __restrict__ xcb) {
    size_t i = (size_t)blockIdx.x * 256 + threadIdx.x;
    int d = (int)(i % Dn);
    int p = (int)(i / Dn);
    int w = p & 63; p >>= 6;
    int h = p & 63; p >>= 6;
    int b = p;
    float acc = cb[d];
#pragma unroll
    for (int kh = 0; kh < 3; kh++) {
        int hh = h + kh - 1;
        if (hh < 0 || hh >= H_) continue;
#pragma unroll
        for (int kw = 0; kw < 3; kw++) {
            int ww = w + kw - 1;
            if (ww < 0 || ww >= W_) continue;
            acc = fmaf(bf2f(xfb[(((size_t)b * H_ + hh) * W_ + ww) * Dn + d]),
                       cw[d * 9 + kh * 3 + kw], acc);
        }
    }
    float sig = 1.f / (1.f + __expf(-acc));
    xcb[i] = f2bf(acc * sig);
}

// ---------------- per-step delta / e1 helper (branchless) -------------------
__device__ __forceinline__ void delta_e1(float x, float& delta, float& e1) {
    float t = __expf(fminf(x, 80.f));
    float opt = 1.f + t;
    delta = __logf(opt);
    e1 = __builtin_amdgcn_rcpf(opt);
}

// packed 12-term dot, 2 parallel chains of 3 pkfma
__device__ __forceinline__ float dot12p(const float4& q0, const float4& q1,
                                        const float4& q2, const f32x2* w2,
                                        float bias) {
    f32x2 a0 = pkfma(lo2(q0), w2[0], mk2(bias, 0.f));
    f32x2 a1 = lo2(q1) * w2[2];
    a0 = pkfma(hi2(q0), w2[1], a0);
    a1 = pkfma(hi2(q1), w2[3], a1);
    a0 = pkfma(lo2(q2), w2[4], a0);
    a1 = pkfma(hi2(q2), w2[5], a1);
    f32x2 s = a0 + a1;
    return s.x + s.y;
}

// scalar 12-term dot (general path)
__device__ __forceinline__ float dot12(const float4& a, const float4& b,
                                       const float4& c, const float* w, float x) {
    x = fmaf(a.x, w[0], x);  x = fmaf(a.y, w[1], x);
    x = fmaf(a.z, w[2], x);  x = fmaf(a.w, w[3], x);
    x = fmaf(b.x, w[4], x);  x = fmaf(b.y, w[5], x);
    x = fmaf(b.z, w[6], x);  x = fmaf(b.w, w[7], x);
    x = fmaf(c.x, w[8], x);  x = fmaf(c.y, w[9], x);
    x = fmaf(c.z, w[10], x); x = fmaf(c.w, w[11], x);
    return x;
}

// ---------------- scan phase 1: per-chunk (prod(a), h_partial) --------------
// LDS: per-step [dt(12) | B(8)] = 5 float4. Fast path is software-pipelined:
// groups of GS=8 steps — loop A (independent dot/softplus chains) then loop B
// (serial h recurrence). Arrays are statically indexed (full unroll).
__global__ __launch_bounds__(192, 4) void k_scan1(const short* __restrict__ xcb,
                                               const float* __restrict__ xdbl,
                                               const float* __restrict__ dtw_all,
                                               const float* __restrict__ dtb_all,
                                               const float* __restrict__ alog,
                                               float* __restrict__ Aprod,
                                               float* __restrict__ hpart) {
    const int blk = blockIdx.x;            // ((b*K + k)*NC + c)
    const int c = blk % NC;
    const int k = (blk / NC) % K_;
    const int b = blk / (NC * K_);
    const int d = threadIdx.x;
    const int t0 = c * CS;
    const int stride = ((k & 1) ? 64 : 1) * ((k >= 2) ? -1 : 1);
    const int lm0 = map_t(k, t0);

    __shared__ float4 sx4[CS][5];
    const float4* xd4 = reinterpret_cast<const float4*>(xdbl);
    for (int i = d; i < CS * 5; i += 192) {
        int ts = i / 5, q = i % 5;
        sx4[ts][q] = xd4[((size_t)b * L_ + lm0 + ts * stride) * 28 + k * 7 + q];
    }
    __syncthreads();

    float dtw[R_];
#pragma unroll
    for (int r = 0; r < R_; r++) dtw[r] = dtw_all[((size_t)k * Dn + d) * R_ + r];
    f32x2 w2[6];
#pragma unroll
    for (int r = 0; r < 6; r++) w2[r] = mk2(dtw[2 * r], dtw[2 * r + 1]);
    const float bias = dtb_all[k * Dn + d];
    float Av[Nst];
    bool fast = true;
#pragma unroll
    for (int n = 0; n < Nst; n++) {
        Av[n] = -__expf(alog[((size_t)k * Dn + d) * Nst + n]);
        fast = fast && (fabsf(Av[n] + (float)(n + 1)) < 1e-3f);
    }

    const long stepD = (long)stride * Dn;
    const short* up = xcb + ((size_t)b * L_ + lm0) * Dn + d;
    size_t base = ((((size_t)(b * K_ + k) * NC + c) * Dn + d)) * Nst;

    if (fast) {
        f32x2 h01 = mk2(0.f, 0.f), h23 = h01, h45 = h01, h67 = h01;
        float p0 = 1.f, p1 = 1.f, p2_ = 1.f, p3_ = 1.f;
        for (int g = 0; g < CS / GS; ++g) {
            const short* ug = up + (long)g * GS * stepD;
            float e1a[GS], dua[GS];
            // loop A: independent chains (dot -> exp -> log -> rcp)
#pragma unroll
            for (int j = 0; j < GS; ++j) {
                int ts = g * GS + j;
                float u = bf2f(ug[(long)j * stepD]);
                float4 q0 = sx4[ts][0], q1 = sx4[ts][1], q2 = sx4[ts][2];
                float delta, e1; delta_e1(dot12p(q0, q1, q2, w2, bias), delta, e1);
                e1a[j] = e1;
                dua[j] = delta * u;
            }
            // loop B: serial h recurrence (only true loop-carried dep)
#pragma unroll
            for (int j = 0; j < GS; ++j) {
                int ts = g * GS + j;
                float e1 = e1a[j], du = dua[j];
                float4 qb0 = sx4[ts][3], qb1 = sx4[ts][4];
                float a2 = e1 * e1;
                f32x2 p12 = mk2(e1, a2);
                f32x2 a22 = mk2(a2, a2);
                f32x2 p34 = a22 * p12;
                f32x2 a44 = mk2(p34.y, p34.y);
                f32x2 p56 = a44 * p12;
                f32x2 p78 = a44 * p34;
                f32x2 du2 = mk2(du, du);
                h01 = pkfma(p12, h01, du2 * lo2(qb0));
                h23 = pkfma(p34, h23, du2 * hi2(qb0));
                h45 = pkfma(p56, h45, du2 * lo2(qb1));
                h67 = pkfma(p78, h67, du2 * hi2(qb1));
            }
            p0 *= e1a[0]; p1 *= e1a[1]; p2_ *= e1a[2]; p3_ *= e1a[3];
            p0 *= e1a[4]; p1 *= e1a[5]; p2_ *= e1a[6]; p3_ *= e1a[7];
        }
        float e1p = (p0 * p1) * (p2_ * p3_);
        float p2 = e1p * e1p, p3 = p2 * e1p, p4 = p2 * p2;
        float4* ap4 = reinterpret_cast<float4*>(Aprod + base);
        ap4[0] = make_float4(e1p, p2, p3, p4);
        ap4[1] = make_float4(p4 * e1p, p4 * p2, p4 * p3, p4 * p4);
        float4* hp4 = reinterpret_cast<float4*>(hpart + base);
        hp4[0] = make_float4(h01.x, h01.y, h23.x, h23.y);
        hp4[1] = make_float4(h45.x, h45.y, h67.x, h67.y);
    } else {
        float h[Nst] = {};
        float Ap[Nst];
#pragma unroll
        for (int n = 0; n < Nst; n++) Ap[n] = 1.f;
        float u_next = bf2f(*up);
        const short* upp = up;
        for (int ts = 0; ts < CS; ts++) {
            float u = u_next;
            upp += stepD;
            if (ts + 1 < CS) u_next = bf2f(*upp);
            float4 q0 = sx4[ts][0], q1 = sx4[ts][1], q2 = sx4[ts][2];
            float4 qb0 = sx4[ts][3], qb1 = sx4[ts][4];
            float Bv[Nst] = {qb0.x, qb0.y, qb0.z, qb0.w, qb1.x, qb1.y, qb1.z, qb1.w};
            float delta, e1; delta_e1(dot12(q0, q1, q2, dtw, bias), delta, e1);
            float du = delta * u;
#pragma unroll
            for (int n = 0; n < Nst; n++) {
                float a = __expf(delta * Av[n]);
                Ap[n] *= a;
                h[n] = fmaf(a, h[n], du * Bv[n]);
            }
        }
#pragma unroll
        for (int n = 0; n < Nst; n++) { Aprod[base + n] = Ap[n]; hpart[base + n] = h[n]; }
    }
}

// ---------------- scan phase 2: chunk-level recurrence -----------------------
__global__ __launch_bounds__(256) void k_scan2(const float* __restrict__ Aprod,
                                               const float* __restrict__ hpart,
                                               float* __restrict__ hin) {
    int idx = blockIdx.x * 256 + threadIdx.x;   // B*K*Dn*Nst = 49152
    int dn = idx % (Dn * Nst);
    int bk = idx / (Dn * Nst);
    size_t stride = (size_t)Dn * Nst;
    size_t base = (size_t)bk * NC * stride + dn;
    float h = 0.f;
    for (int cc = 0; cc < NC; cc++) {
        size_t s = base + (size_t)cc * stride;
        hin[s] = h;
        h = fmaf(Aprod[s], h, hpart[s]);
    }
}

// ---------------- scan phase 3: recompute with h_in, emit y -----------------
// LDS: per-step [dt(12) | B(8) | C(8)] = 7 float4. Pipelined like scan1.
__global__ __launch_bounds__(192, 4) void k_scan3(const short* __restrict__ xcb,
                                               const float* __restrict__ xdbl,
                                               const float* __restrict__ dtw_all,
                                               const float* __restrict__ dtb_all,
                                               const float* __restrict__ alog,
                                               const float* __restrict__ dvec,
                                               const float* __restrict__ hin,
                                               short* __restrict__ y0,
                                               short* __restrict__ y1,
                                               short* __restrict__ y2,
                                               short* __restrict__ y3) {
    const int blk = blockIdx.x;
    const int c = blk % NC;
    const int k = (blk / NC) % K_;
    const int b = blk / (NC * K_);
    const int d = threadIdx.x;
    const int t0 = c * CS;
    const int stride = ((k & 1) ? 64 : 1) * ((k >= 2) ? -1 : 1);
    const int lm0 = map_t(k, t0);
    short* __restrict__ yk = (k == 0) ? y0 : (k == 1) ? y1 : (k == 2) ? y2 : y3;

    __shared__ float4 sx4[CS][7];
    const float4* xd4 = reinterpret_cast<const float4*>(xdbl);
    for (int i = d; i < CS * 7; i += 192) {
        int ts = i / 7, q = i % 7;
        sx4[ts][q] = xd4[((size_t)b * L_ + lm0 + ts * stride) * 28 + k * 7 + q];
    }
    __syncthreads();

    float dtw[R_];
#pragma unroll
    for (int r = 0; r < R_; r++) dtw[r] = dtw_all[((size_t)k * Dn + d) * R_ + r];
    f32x2 w2[6];
#pragma unroll
    for (int r = 0; r < 6; r++) w2[r] = mk2(dtw[2 * r], dtw[2 * r + 1]);
    const float bias = dtb_all[k * Dn + d];
    const float Dk = dvec[k * Dn + d];
    float Av[Nst];
    bool fast = true;
#pragma unroll
    for (int n = 0; n < Nst; n++) {
        Av[n] = -__expf(alog[((size_t)k * Dn + d) * Nst + n]);
        fast = fast && (fabsf(Av[n] + (float)(n + 1)) < 1e-3f);
    }

    size_t hbase = ((((size_t)(b * K_ + k) * NC + c) * Dn + d)) * Nst;
    const long stepD = (long)stride * Dn;
    const short* up = xcb + ((size_t)b * L_ + lm0) * Dn + d;
    short* yp = yk + ((size_t)b * L_ + lm0) * Dn + d;

    if (fast) {
        const float4* hi4 = reinterpret_cast<const float4*>(hin + hbase);
        float4 ha = hi4[0], hb = hi4[1];
        f32x2 h01 = lo2(ha), h23 = hi2(ha), h45 = lo2(hb), h67 = hi2(hb);
        for (int g = 0; g < CS / GS; ++g) {
            const short* ug = up + (long)g * GS * stepD;
            short* yg = yp + (long)g * GS * stepD;
            float e1a[GS], dua[GS], dku[GS];
            // loop A: independent chains
#pragma unroll
            for (int j = 0; j < GS; ++j) {
                int ts = g * GS + j;
                float u = bf2f(ug[(long)j * stepD]);
                float4 q0 = sx4[ts][0], q1 = sx4[ts][1], q2 = sx4[ts][2];
                float delta, e1; delta_e1(dot12p(q0, q1, q2, w2, bias), delta, e1);
                e1a[j] = e1;
                dua[j] = delta * u;
                dku[j] = Dk * u;
            }
            // loop B: serial h recurrence + y emission
#pragma unroll
            for (int j = 0; j < GS; ++j) {
                int ts = g * GS + j;
                float e1 = e1a[j], du = dua[j];
                float4 qb0 = sx4[ts][3], qb1 = sx4[ts][4];
                float4 qc0 = sx4[ts][5], qc1 = sx4[ts][6];
                float a2 = e1 * e1;
                f32x2 p12 = mk2(e1, a2);
                f32x2 a22 = mk2(a2, a2);
                f32x2 p34 = a22 * p12;
                f32x2 a44 = mk2(p34.y, p34.y);
                f32x2 p56 = a44 * p12;
                f32x2 p78 = a44 * p34;
                f32x2 du2 = mk2(du, du);
                h01 = pkfma(p12, h01, du2 * lo2(qb0));
                h23 = pkfma(p34, h23, du2 * hi2(qb0));
                h45 = pkfma(p56, h45, du2 * lo2(qb1));
                h67 = pkfma(p78, h67, du2 * hi2(qb1));
                f32x2 yacc = mk2(dku[j], 0.f);
                yacc = pkfma(h01, lo2(qc0), yacc);
                yacc = pkfma(h23, hi2(qc0), yacc);
                yacc = pkfma(h45, lo2(qc1), yacc);
                yacc = pkfma(h67, hi2(qc1), yacc);
                yg[(long)j * stepD] = f2bf(yacc.x + yacc.y);
            }
        }
    } else {
        float h[Nst];
#pragma unroll
        for (int n = 0; n < Nst; n++) h[n] = hin[hbase + n];
        float u_next = bf2f(*up);
        const short* upp = up;
        short* ypp = yp;
        for (int ts = 0; ts < CS; ts++) {
            float u = u_next;
            upp += stepD;
            if (ts + 1 < CS) u_next = bf2f(*upp);
            float4 q0 = sx4[ts][0], q1 = sx4[ts][1], q2 = sx4[ts][2];
            float4 qb0 = sx4[ts][3], qb1 = sx4[ts][4];
            float4 qc0 = sx4[ts][5], qc1 = sx4[ts][6];
            float Bv[Nst] = {qb0.x, qb0.y, qb0.z, qb0.w, qb1.x, qb1.y, qb1.z, qb1.w};
            float Cv[Nst] = {qc0.x, qc0.y, qc0.z, qc0.w, qc1.x, qc1.y, qc1.z, qc1.w};
            float delta, e1; delta_e1(dot12(q0, q1, q2, dtw, bias), delta, e1);
            float du = delta * u;
            float y = Dk * u;
#pragma unroll
            for (int n = 0; n < Nst; n++) {
                float a = __expf(delta * Av[n]);
                h[n] = fmaf(a, h[n], du * Bv[n]);
                y = fmaf(h[n], Cv[n], y);
            }
            *ypp = f2bf(y);
            ypp += stepD;
        }
    }
}

// ---------------- merge 4 dirs + LayerNorm(Dn) * SiLU(z) -> bf16 ------------
__global__ __launch_bounds__(256) void k_ln(const short* __restrict__ y0,
                                            const short* __restrict__ y1,
                                            const short* __restrict__ y2,
                                            const short* __restrict__ y3,
                                            const short* __restrict__ zb,
                                            const float* __restrict__ lnw,
                                            const float* __restrict__ lnb,
                                            short* __restrict__ yfin) {
    const int row = blockIdx.x * 4 + (threadIdx.x >> 6);
    const int lane = threadIdx.x & 63;
    const size_t base = (size_t)row * Dn;
    float v[3];
    float s = 0.f, s2 = 0.f;
#pragma unroll
    for (int j = 0; j < 3; j++) {
        size_t idx = base + lane + j * 64;
        v[j] = bf2f(y0[idx]) + bf2f(y1[idx]) + bf2f(y2[idx]) + bf2f(y3[idx]);
        s += v[j];
        s2 = fmaf(v[j], v[j], s2);
    }
#pragma unroll
    for (int o = 1; o < 64; o <<= 1) {
        s += __shfl_xor(s, o);
        s2 += __shfl_xor(s2, o);
    }
    const float inv = 1.f / 192.f;
    float mu = s * inv;
    float var = s2 * inv - mu * mu;
    float rstd = rsqrtf(var + 1e-5f);
#pragma unroll
    for (int j = 0; j < 3; j++) {
        int dd = lane + j * 64;
        size_t idx = base + dd;
        float zz = bf2f(zb[idx]);
        float sig = 1.f / (1.f + __expf(-zz));
        float res = ((v[j] - mu) * rstd * lnw[dd] + lnb[dd]) * (zz * sig);
        yfin[idx] = f2bf(res);
    }
}

// ---------------- launcher ---------------------------------------------------
extern "C" void kernel_launch(void* const* d_in, const int* in_sizes, int n_in,
                              void* d_out, int out_size, void* d_ws, size_t ws_size,
                              hipStream_t stream) {
    const float* x    = (const float*)d_in[0];
    const float* w_in = (const float*)d_in[1];
    const float* cw   = (const float*)d_in[2];
    const float* cb   = (const float*)d_in[3];
    const float* xpw  = (const float*)d_in[4];
    const float* dtw  = (const float*)d_in[5];
    const float* dtb  = (const float*)d_in[6];
    const float* alog = (const float*)d_in[7];
    const float* dvec = (const float*)d_in[8];
    const float* lnw  = (const float*)d_in[9];
    const float* lnb  = (const float*)d_in[10];
    const float* wout = (const float*)d_in[11];
    float* out = (float*)d_out;

    const size_t SH  = (size_t)MROWS * Dn;               // 6,291,456 elems
    const size_t SCN = (size_t)B_ * K_ * NC * Dn * Nst;  // 6,291,456 elems

    char* p = (char*)d_ws;
    short* x_bf  = (short*)p; p += SH * 2;               // region0 -> y0
    short* xf_bf = (short*)p; p += SH * 2;               // region1 -> y1
    short* z_bf  = (short*)p; p += SH * 2;               // region2
    short* xc_bf = (short*)p; p += SH * 2;               // region3
    float* xdbl  = (float*)p; p += (size_t)MROWS * (K_ * CPROJ) * 4;
    float* Aprod = (float*)p; p += SCN * 4;              // region5 -> y2
    float* hpart = (float*)p; p += SCN * 4;              // region6 -> y3
    float* hin   = (float*)p; p += SCN * 4;              // region7 -> yfin
    short* w_bf  = (short*)p;
    // aliases (lifetimes): y0<-x_bf (dead after in_proj), y1<-xf_bf (dead after
    // conv), y2<-Aprod, y3<-hpart (dead after scan2), yfin<-hin (dead after
    // scan3; k_ln runs after scan3).
    short* y0 = x_bf;
    short* y1 = xf_bf;
    short* y2 = (short*)Aprod;
    short* y3 = (short*)hpart;
    short* yfin_bf = (short*)hin;

    // 0. fused converts
    k_cvt<<<(XUNITS + WUNITS + 255) / 256, 256, 0, stream>>>(x, w_in, xpw, wout,
                                                             x_bf, w_bf);
    // 1. in_proj (MFMA) -> xf_bf, z_bf
    k_mgemm_in<<<dim3(MROWS / 128, 6), 256, 0, stream>>>(x_bf, w_bf + WOFF_IN,
                                                         xf_bf, z_bf, C_);
    // 2. depthwise conv 3x3 + SiLU -> xc_bf
    k_conv<<<(int)(SH / 256), 256, 0, stream>>>(xf_bf, cw, cb, xc_bf);
    // 3. x_dbl (all 4 dirs, one MFMA GEMM) -> f32
    k_mgemm_f<<<dim3(MROWS / 128, 2), 256, 0, stream>>>(xc_bf, w_bf + WOFF_XP,
                                                        xdbl, K_ * CPROJ, Dn);
    // 4-6. chunked parallel selective scan (CS=32, software-pipelined groups)
    k_scan1<<<B_ * K_ * NC, 192, 0, stream>>>(xc_bf, xdbl, dtw, dtb, alog, Aprod, hpart);
    k_scan2<<<(B_ * K_ * Dn * Nst) / 256, 256, 0, stream>>>(Aprod, hpart, hin);
    k_scan3<<<B_ * K_ * NC, 192, 0, stream>>>(xc_bf, xdbl, dtw, dtb, alog, dvec,
                                              hin, y0, y1, y2, y3);
    // 7. merge + LayerNorm * SiLU(z) -> bf16
    k_ln<<<MROWS / 4, 256, 0, stream>>>(y0, y1, y2, y3, z_bf, lnw, lnb, yfin_bf);
    // 8. out_proj (MFMA) -> d_out (f32)
    k_mgemm_f<<<dim3(MROWS / 128, 3), 256, 0, stream>>>(yfin_bf, w_bf + WOFF_OUT,
                                                        out, C_, Dn);
}